// Round 1
// 1351.035 us; speedup vs baseline: 1.4490x; 1.4490x over previous
//
#include <hip/hip_runtime.h>
#include <stdint.h>

#define NEG_SLOPE 0.01f
#define EPSF 1e-10f
#define NB_SHIFT 11
#define NB_ROWS (1 << NB_SHIFT)   // 2048 rows per bucket
#define NB_MAX 512                // supports N up to 2^20

__device__ __forceinline__ float lrelu(float x){
  return fmaxf(x, 0.f) + NEG_SLOPE * fminf(x, 0.f);
}

// K0: repack W [2][64][32] fp32 -> Wf [64 k][64 j] (j = c*32+jj), b -> bf[64]
__global__ void conv_wb(const float* __restrict__ W,
                        const float* __restrict__ b,
                        float* __restrict__ Wf, float* __restrict__ bf){
  int i = blockIdx.x * blockDim.x + threadIdx.x;
  for (int idx = i; idx < 64 * 64; idx += blockDim.x * gridDim.x){
    int k = idx >> 6, j = idx & 63;
    int c = j >> 5, jj = j & 31;
    Wf[idx] = W[c * 2048 + k * 32 + jj];
  }
  if (i < 64) bf[i] = b[i];   // b flat [2][1][32] already matches j = c*32+jj
}

// K1: projection. One thread per node: h[n][j] = leaky(sum_k ego[n][k]*Wf[k][j] + bf[j])
__global__ __launch_bounds__(256) void proj(const float* __restrict__ ego,
                                            const float* __restrict__ Wf,
                                            const float* __restrict__ bf,
                                            float* __restrict__ h, int N){
  int n = blockIdx.x * 256 + threadIdx.x;
  if (n >= N) return;
  float acc[64];
  #pragma unroll
  for (int j = 0; j < 64; j++) acc[j] = bf[j];
  const float4* ep = (const float4*)(ego + (size_t)n * 64);
  for (int kk = 0; kk < 16; kk++){
    float4 q = ep[kk];
    float ev[4] = {q.x, q.y, q.z, q.w};
    const float* wbase = Wf + kk * 4 * 64;   // uniform address -> s_load expected
    #pragma unroll
    for (int t = 0; t < 4; t++){
      float ek = ev[t];
      const float* wrow = wbase + t * 64;
      #pragma unroll
      for (int j = 0; j < 64; j++) acc[j] = fmaf(ek, wrow[j], acc[j]);
    }
  }
  float4* hp = (float4*)(h + (size_t)n * 64);
  #pragma unroll
  for (int v = 0; v < 16; v++){
    float4 o;
    o.x = lrelu(acc[4 * v + 0]);
    o.y = lrelu(acc[4 * v + 1]);
    o.z = lrelu(acc[4 * v + 2]);
    o.w = lrelu(acc[4 * v + 3]);
    hp[v] = o;
  }
}

// K2: bucket histogram (LDS-staged). bucket = row >> NB_SHIFT
__global__ __launch_bounds__(256) void bhist(const int* __restrict__ row,
                                             int* __restrict__ bcnt, int E, int nb){
  __shared__ int lh[NB_MAX];
  for (int i = threadIdx.x; i < nb; i += 256) lh[i] = 0;
  __syncthreads();
  int i = blockIdx.x * 256 + threadIdx.x;
  int stride = gridDim.x * 256;
  for (; i < E; i += stride) atomicAdd(&lh[row[i] >> NB_SHIFT], 1);
  __syncthreads();
  for (int j = threadIdx.x; j < nb; j += 256){
    int v = lh[j];
    if (v) atomicAdd(&bcnt[j], v);
  }
}

// K3: exclusive scan of bucket counts (nb <= 512), init bucket cursors
__global__ __launch_bounds__(512) void bscan(const int* __restrict__ bcnt,
                                             int* __restrict__ bbase,
                                             int* __restrict__ bcur, int nb){
  __shared__ int sh[NB_MAX];
  int t = threadIdx.x;
  int v = (t < nb) ? bcnt[t] : 0;
  sh[t] = v; __syncthreads();
  for (int off = 1; off < NB_MAX; off <<= 1){
    int a = (t >= off) ? sh[t - off] : 0;
    __syncthreads();
    sh[t] += a;
    __syncthreads();
  }
  if (t < nb){
    int e = sh[t] - v;
    bbase[t] = e;
    bcur[t] = e;
  }
}

// K4: bin edges into bucket-contiguous tmp, packed (rowLow11 << 20) | col
// per-block chunk reservation -> ~134B contiguous runs per bucket per block
__global__ __launch_bounds__(256) void binpairs(const int* __restrict__ row,
                                                const int* __restrict__ col,
                                                int* __restrict__ bcur,
                                                unsigned int* __restrict__ tmp,
                                                int E, int nb){
  const int EPT = 32;
  __shared__ int lh[NB_MAX];     // per-chunk histogram, then reused as cursor
  __shared__ int lbase[NB_MAX];  // reserved global base per bucket
  for (int i = threadIdx.x; i < nb; i += 256) lh[i] = 0;
  __syncthreads();
  int chunk0 = blockIdx.x * (256 * EPT);
  int r[EPT], c[EPT];
  #pragma unroll
  for (int k = 0; k < EPT; k++){
    int e = chunk0 + k * 256 + threadIdx.x;
    if (e < E){
      r[k] = row[e];
      c[k] = col[e];
      atomicAdd(&lh[r[k] >> NB_SHIFT], 1);
    } else r[k] = -1;
  }
  __syncthreads();
  for (int i = threadIdx.x; i < nb; i += 256){
    int cnt = lh[i];
    lbase[i] = cnt ? atomicAdd(&bcur[i], cnt) : 0;
  }
  __syncthreads();
  for (int i = threadIdx.x; i < nb; i += 256) lh[i] = 0;
  __syncthreads();
  #pragma unroll
  for (int k = 0; k < EPT; k++){
    if (r[k] >= 0){
      int b = r[k] >> NB_SHIFT;
      int off = atomicAdd(&lh[b], 1);
      unsigned int packed = ((unsigned int)(r[k] & (NB_ROWS - 1)) << 20) | (unsigned int)c[k];
      tmp[lbase[b] + off] = packed;
    }
  }
}

// K5: per-bucket CSR finalize. One block per bucket:
// LDS row histogram -> LDS scan -> deg/offs coalesced -> scatter colp into
// contiguous ~64KB window (L2-resident writes).
__global__ __launch_bounds__(256) void csrbuild(const unsigned int* __restrict__ tmp,
                                                const int* __restrict__ bbase,
                                                const int* __restrict__ bcnt,
                                                int* __restrict__ deg,
                                                int* __restrict__ offs,
                                                int* __restrict__ colp,
                                                int N){
  int b = blockIdx.x;
  int r0 = b << NB_SHIFT;
  __shared__ int cnt[NB_ROWS];
  __shared__ int wsum[256];
  int t = threadIdx.x;
  for (int i = t; i < NB_ROWS; i += 256) cnt[i] = 0;
  __syncthreads();
  int s = bbase[b];
  int e = s + bcnt[b];
  for (int p = s + t; p < e; p += 256){
    unsigned int v = tmp[p];
    atomicAdd(&cnt[v >> 20], 1);
  }
  __syncthreads();
  // block scan over 2048 counts: 8 owned values per thread
  int base_i = t * 8;
  int dv[8], loc[8];
  int sum = 0;
  #pragma unroll
  for (int k = 0; k < 8; k++){
    dv[k] = cnt[base_i + k];
    loc[k] = sum;
    sum += dv[k];
  }
  wsum[t] = sum; __syncthreads();
  for (int off = 1; off < 256; off <<= 1){
    int a = (t >= off) ? wsum[t - off] : 0;
    __syncthreads();
    wsum[t] += a;
    __syncthreads();
  }
  int tbase = wsum[t] - sum;
  #pragma unroll
  for (int k = 0; k < 8; k++){
    int i = base_i + k;
    int o = tbase + loc[k];
    if (r0 + i < N){
      deg[r0 + i] = dv[k];
      offs[r0 + i] = s + o;
    }
    cnt[i] = o;   // local cursor (own entries only; safe pre-barrier)
  }
  __syncthreads();
  for (int p = s + t; p < e; p += 256){
    unsigned int v = tmp[p];
    int rl = (int)(v >> 20);
    int pos = atomicAdd(&cnt[rl], 1);
    colp[s + pos] = (int)(v & 0xFFFFFu);
  }
}

// K6: fused per-(node, channel) attention aggregation
__global__ __launch_bounds__(256) void agg(const float* __restrict__ h,
                                           const int* __restrict__ offs,
                                           const int* __restrict__ deg,
                                           const int* __restrict__ colp,
                                           float* __restrict__ out, int N){
  int n = blockIdx.x * 256 + threadIdx.x;
  int ch = blockIdx.y;
  if (n >= N) return;
  const float4* hr4 = (const float4*)(h + (size_t)n * 64 + ch * 32);
  float hr[32];
  #pragma unroll
  for (int v = 0; v < 8; v++){
    float4 q = hr4[v];
    hr[4 * v + 0] = q.x; hr[4 * v + 1] = q.y; hr[4 * v + 2] = q.z; hr[4 * v + 3] = q.w;
  }
  float acc[32];
  #pragma unroll
  for (int j = 0; j < 32; j++) acc[j] = 0.f;
  float l = 0.f;
  int s = offs[n], d = deg[n];
  for (int p = s; p < s + d; ++p){
    int c = colp[p];
    const float4* hc4 = (const float4*)(h + (size_t)c * 64 + ch * 32);
    float hc[32];
    #pragma unroll
    for (int v = 0; v < 8; v++){
      float4 q = hc4[v];
      hc[4 * v + 0] = q.x; hc[4 * v + 1] = q.y; hc[4 * v + 2] = q.z; hc[4 * v + 3] = q.w;
    }
    float dot = 0.f;
    #pragma unroll
    for (int j = 0; j < 32; j++) dot = fmaf(hr[j], hc[j], dot);
    float lg = fminf(lrelu(dot), 80.f);
    float w = __expf(lg);
    l += w;
    #pragma unroll
    for (int j = 0; j < 32; j++) acc[j] = fmaf(w, hc[j], acc[j]);
  }
  float inv = 1.f / (l + EPSF);
  float4* op = (float4*)(out + (size_t)n * 64 + ch * 32);
  #pragma unroll
  for (int v = 0; v < 8; v++){
    float4 o;
    o.x = acc[4 * v + 0] * inv;
    o.y = acc[4 * v + 1] * inv;
    o.z = acc[4 * v + 2] * inv;
    o.w = acc[4 * v + 3] * inv;
    op[v] = o;
  }
}

extern "C" void kernel_launch(void* const* d_in, const int* in_sizes, int n_in,
                              void* d_out, int out_size, void* d_ws, size_t ws_size,
                              hipStream_t stream){
  const float* ego = (const float*)d_in[0];
  const float* W   = (const float*)d_in[1];
  const float* b   = (const float*)d_in[2];
  const int* row = (const int*)d_in[3];
  const int* col = (const int*)d_in[4];
  int N = in_sizes[0] / 64;
  int E = in_sizes[3];
  float* out = (float*)d_out;

  char* ws = (char*)d_ws;
  float* Wf = (float*)ws;                       // 4096 f
  float* bf = Wf + 4096;                        // 64 f
  size_t off = 32768;
  float* h = (float*)(ws + off); off += (size_t)N * 64 * 4;
  int* deg  = (int*)(ws + off); off += (size_t)N * 4;
  int* offs = (int*)(ws + off); off += (size_t)N * 4;
  int* bcnt  = (int*)(ws + off); off += NB_MAX * 4;
  int* bbase = (int*)(ws + off); off += NB_MAX * 4;
  int* bcur  = (int*)(ws + off); off += NB_MAX * 4;
  unsigned int* tmp = (unsigned int*)(ws + off); off += (size_t)E * 4;
  int* colp = (int*)(ws + off);

  int nb = (N + NB_ROWS - 1) >> NB_SHIFT;       // 489 for N=1e6

  hipMemsetAsync(bcnt, 0, NB_MAX * 4, stream);
  conv_wb<<<16, 256, 0, stream>>>(W, b, Wf, bf);
  proj<<<(N + 255) / 256, 256, 0, stream>>>(ego, Wf, bf, h, N);
  bhist<<<256, 256, 0, stream>>>(row, bcnt, E, nb);
  bscan<<<1, NB_MAX, 0, stream>>>(bcnt, bbase, bcur, nb);
  binpairs<<<(E + 256 * 32 - 1) / (256 * 32), 256, 0, stream>>>(row, col, bcur, tmp, E, nb);
  csrbuild<<<nb, 256, 0, stream>>>(tmp, bbase, bcnt, deg, offs, colp, N);
  dim3 g((N + 255) / 256, 2);
  agg<<<g, 256, 0, stream>>>(h, offs, deg, colp, out, N);
}

// Round 2
// 1274.002 us; speedup vs baseline: 1.5367x; 1.0605x over previous
//
#include <hip/hip_runtime.h>
#include <stdint.h>

#define NEG_SLOPE 0.01f
#define EPSF 1e-10f
#define NB_SHIFT 11
#define NB_ROWS (1 << NB_SHIFT)   // 2048 rows per bucket
#define NB_MAX 512                // supports N up to 2^20
#define BP_EPT 16
#define BP_EDGES (256 * BP_EPT)   // 4096 edges per binpairs block
#define CB_CAP 20480              // csrbuild LDS staging capacity (mean 16384, sigma ~128)

__device__ __forceinline__ float lrelu(float x){
  return fmaxf(x, 0.f) + NEG_SLOPE * fminf(x, 0.f);
}

// K0: repack W [2][64][32] fp32 -> Wf [64 k][64 j] (j = c*32+jj), b -> bf[64]
__global__ void conv_wb(const float* __restrict__ W,
                        const float* __restrict__ b,
                        float* __restrict__ Wf, float* __restrict__ bf){
  int i = blockIdx.x * blockDim.x + threadIdx.x;
  for (int idx = i; idx < 64 * 64; idx += blockDim.x * gridDim.x){
    int k = idx >> 6, j = idx & 63;
    int c = j >> 5, jj = j & 31;
    Wf[idx] = W[c * 2048 + k * 32 + jj];
  }
  if (i < 64) bf[i] = b[i];
}

// K1: projection
__global__ __launch_bounds__(256) void proj(const float* __restrict__ ego,
                                            const float* __restrict__ Wf,
                                            const float* __restrict__ bf,
                                            float* __restrict__ h, int N){
  int n = blockIdx.x * 256 + threadIdx.x;
  if (n >= N) return;
  float acc[64];
  #pragma unroll
  for (int j = 0; j < 64; j++) acc[j] = bf[j];
  const float4* ep = (const float4*)(ego + (size_t)n * 64);
  for (int kk = 0; kk < 16; kk++){
    float4 q = ep[kk];
    float ev[4] = {q.x, q.y, q.z, q.w};
    const float* wbase = Wf + kk * 4 * 64;
    #pragma unroll
    for (int t = 0; t < 4; t++){
      float ek = ev[t];
      const float* wrow = wbase + t * 64;
      #pragma unroll
      for (int j = 0; j < 64; j++) acc[j] = fmaf(ek, wrow[j], acc[j]);
    }
  }
  float4* hp = (float4*)(h + (size_t)n * 64);
  #pragma unroll
  for (int v = 0; v < 16; v++){
    float4 o;
    o.x = lrelu(acc[4 * v + 0]);
    o.y = lrelu(acc[4 * v + 1]);
    o.z = lrelu(acc[4 * v + 2]);
    o.w = lrelu(acc[4 * v + 3]);
    hp[v] = o;
  }
}

// K2: bucket histogram (LDS-staged). bucket = row >> NB_SHIFT
__global__ __launch_bounds__(256) void bhist(const int* __restrict__ row,
                                             int* __restrict__ bcnt, int E, int nb){
  __shared__ int lh[NB_MAX];
  for (int i = threadIdx.x; i < nb; i += 256) lh[i] = 0;
  __syncthreads();
  int i = blockIdx.x * 256 + threadIdx.x;
  int stride = gridDim.x * 256;
  for (; i < E; i += stride) atomicAdd(&lh[row[i] >> NB_SHIFT], 1);
  __syncthreads();
  for (int j = threadIdx.x; j < nb; j += 256){
    int v = lh[j];
    if (v) atomicAdd(&bcnt[j], v);
  }
}

// K3: exclusive scan of bucket counts, init bucket cursors
__global__ __launch_bounds__(512) void bscan(const int* __restrict__ bcnt,
                                             int* __restrict__ bbase,
                                             int* __restrict__ bcur, int nb){
  __shared__ int sh[NB_MAX];
  int t = threadIdx.x;
  int v = (t < nb) ? bcnt[t] : 0;
  sh[t] = v; __syncthreads();
  for (int off = 1; off < NB_MAX; off <<= 1){
    int a = (t >= off) ? sh[t - off] : 0;
    __syncthreads();
    sh[t] += a;
    __syncthreads();
  }
  if (t < nb){
    int e = sh[t] - v;
    bbase[t] = e;
    bcur[t] = e;
  }
}

// K4: bin edges into bucket-contiguous tmp, LDS-sorted so global writes
// are coalesced within per-(block,bucket) runs. packed = (rowLow11<<20)|col
__global__ __launch_bounds__(256) void binpairs(const int* __restrict__ row,
                                                const int* __restrict__ col,
                                                int* __restrict__ bcur,
                                                unsigned int* __restrict__ tmp,
                                                int E, int nb){
  __shared__ int lh[NB_MAX];             // per-chunk bucket counts
  __shared__ int lofs[NB_MAX];           // exclusive offsets within chunk
  __shared__ int lbase[NB_MAX];          // reserved global base per bucket
  __shared__ int wsum[256];
  __shared__ unsigned int sval[BP_EDGES];
  __shared__ unsigned int sdst[BP_EDGES];
  int t = threadIdx.x;
  for (int i = t; i < nb; i += 256) lh[i] = 0;
  __syncthreads();
  int e0 = blockIdx.x * BP_EDGES;
  int tot = E - e0; if (tot > BP_EDGES) tot = BP_EDGES;
  int r[BP_EPT], c[BP_EPT], mo[BP_EPT];
  #pragma unroll
  for (int k = 0; k < BP_EPT; k++){
    int e = e0 + k * 256 + t;
    if (e < E){
      r[k] = row[e];
      c[k] = col[e];
      mo[k] = atomicAdd(&lh[r[k] >> NB_SHIFT], 1);
    } else r[k] = -1;
  }
  __syncthreads();
  // scan lh over nb (<=512) buckets: 2 per thread + Hillis-Steele over 256
  int c0 = (2 * t < nb) ? lh[2 * t] : 0;
  int c1 = (2 * t + 1 < nb) ? lh[2 * t + 1] : 0;
  int s = c0 + c1;
  wsum[t] = s; __syncthreads();
  for (int off = 1; off < 256; off <<= 1){
    int a = (t >= off) ? wsum[t - off] : 0;
    __syncthreads();
    wsum[t] += a;
    __syncthreads();
  }
  int tb = wsum[t] - s;
  if (2 * t < nb){
    lofs[2 * t] = tb;
    if (c0) lbase[2 * t] = atomicAdd(&bcur[2 * t], c0);
  }
  if (2 * t + 1 < nb){
    lofs[2 * t + 1] = tb + c0;
    if (c1) lbase[2 * t + 1] = atomicAdd(&bcur[2 * t + 1], c1);
  }
  __syncthreads();
  // stage into LDS in bucket-sorted order
  #pragma unroll
  for (int k = 0; k < BP_EPT; k++){
    if (r[k] >= 0){
      int b = r[k] >> NB_SHIFT;
      int slot = lofs[b] + mo[k];
      sval[slot] = ((unsigned int)(r[k] & (NB_ROWS - 1)) << 20) | (unsigned int)c[k];
      sdst[slot] = (unsigned int)(lbase[b] + mo[k]);
    }
  }
  __syncthreads();
  // writeout: consecutive lanes -> consecutive global addrs within runs
  for (int i = t; i < tot; i += 256) tmp[sdst[i]] = sval[i];
}

// K5: per-bucket CSR finalize. LDS row hist -> scan -> deg/offs coalesced ->
// LDS-staged row-sorted cols -> fully coalesced colp write.
__global__ __launch_bounds__(512) void csrbuild(const unsigned int* __restrict__ tmp,
                                                const int* __restrict__ bbase,
                                                const int* __restrict__ bcnt,
                                                int* __restrict__ deg,
                                                int* __restrict__ offs,
                                                int* __restrict__ colp,
                                                int N){
  __shared__ int cnt[NB_ROWS];
  __shared__ int wsum[512];
  __shared__ int scol[CB_CAP];
  int b = blockIdx.x;
  int r0 = b << NB_SHIFT;
  int t = threadIdx.x;
  for (int i = t; i < NB_ROWS; i += 512) cnt[i] = 0;
  __syncthreads();
  int s = bbase[b];
  int cb = bcnt[b];
  int e = s + cb;
  for (int p = s + t; p < e; p += 512) atomicAdd(&cnt[tmp[p] >> 20], 1);
  __syncthreads();
  // block scan over 2048 counts: 4 owned per thread
  int base_i = t * 4;
  int dv[4], loc[4];
  int sum = 0;
  #pragma unroll
  for (int k = 0; k < 4; k++){
    dv[k] = cnt[base_i + k];
    loc[k] = sum;
    sum += dv[k];
  }
  wsum[t] = sum; __syncthreads();
  for (int off = 1; off < 512; off <<= 1){
    int a = (t >= off) ? wsum[t - off] : 0;
    __syncthreads();
    wsum[t] += a;
    __syncthreads();
  }
  int tbase = wsum[t] - sum;
  #pragma unroll
  for (int k = 0; k < 4; k++){
    int i = base_i + k;
    int o = tbase + loc[k];
    if (r0 + i < N){
      deg[r0 + i] = dv[k];
      offs[r0 + i] = s + o;
    }
    cnt[i] = o;   // local cursor
  }
  __syncthreads();
  if (cb <= CB_CAP){
    for (int p = s + t; p < e; p += 512){
      unsigned int v = tmp[p];
      int pos = atomicAdd(&cnt[v >> 20], 1);
      scol[pos] = (int)(v & 0xFFFFFu);
    }
    __syncthreads();
    for (int i = t; i < cb; i += 512) colp[s + i] = scol[i];
  } else {
    // statistically unreachable fallback
    for (int p = s + t; p < e; p += 512){
      unsigned int v = tmp[p];
      int pos = atomicAdd(&cnt[v >> 20], 1);
      colp[s + pos] = (int)(v & 0xFFFFFu);
    }
  }
}

// K6: fused per-(node, channel) attention aggregation
__global__ __launch_bounds__(256) void agg(const float* __restrict__ h,
                                           const int* __restrict__ offs,
                                           const int* __restrict__ deg,
                                           const int* __restrict__ colp,
                                           float* __restrict__ out, int N){
  int n = blockIdx.x * 256 + threadIdx.x;
  int ch = blockIdx.y;
  if (n >= N) return;
  const float4* hr4 = (const float4*)(h + (size_t)n * 64 + ch * 32);
  float hr[32];
  #pragma unroll
  for (int v = 0; v < 8; v++){
    float4 q = hr4[v];
    hr[4 * v + 0] = q.x; hr[4 * v + 1] = q.y; hr[4 * v + 2] = q.z; hr[4 * v + 3] = q.w;
  }
  float acc[32];
  #pragma unroll
  for (int j = 0; j < 32; j++) acc[j] = 0.f;
  float l = 0.f;
  int s = offs[n], d = deg[n];
  for (int p = s; p < s + d; ++p){
    int c = colp[p];
    const float4* hc4 = (const float4*)(h + (size_t)c * 64 + ch * 32);
    float hc[32];
    #pragma unroll
    for (int v = 0; v < 8; v++){
      float4 q = hc4[v];
      hc[4 * v + 0] = q.x; hc[4 * v + 1] = q.y; hc[4 * v + 2] = q.z; hc[4 * v + 3] = q.w;
    }
    float dot = 0.f;
    #pragma unroll
    for (int j = 0; j < 32; j++) dot = fmaf(hr[j], hc[j], dot);
    float lg = fminf(lrelu(dot), 80.f);
    float w = __expf(lg);
    l += w;
    #pragma unroll
    for (int j = 0; j < 32; j++) acc[j] = fmaf(w, hc[j], acc[j]);
  }
  float inv = 1.f / (l + EPSF);
  float4* op = (float4*)(out + (size_t)n * 64 + ch * 32);
  #pragma unroll
  for (int v = 0; v < 8; v++){
    float4 o;
    o.x = acc[4 * v + 0] * inv;
    o.y = acc[4 * v + 1] * inv;
    o.z = acc[4 * v + 2] * inv;
    o.w = acc[4 * v + 3] * inv;
    op[v] = o;
  }
}

extern "C" void kernel_launch(void* const* d_in, const int* in_sizes, int n_in,
                              void* d_out, int out_size, void* d_ws, size_t ws_size,
                              hipStream_t stream){
  const float* ego = (const float*)d_in[0];
  const float* W   = (const float*)d_in[1];
  const float* b   = (const float*)d_in[2];
  const int* row = (const int*)d_in[3];
  const int* col = (const int*)d_in[4];
  int N = in_sizes[0] / 64;
  int E = in_sizes[3];
  float* out = (float*)d_out;

  char* ws = (char*)d_ws;
  float* Wf = (float*)ws;                       // 4096 f
  float* bf = Wf + 4096;                        // 64 f
  size_t off = 32768;
  float* h = (float*)(ws + off); off += (size_t)N * 64 * 4;
  int* deg  = (int*)(ws + off); off += (size_t)N * 4;
  int* offs = (int*)(ws + off); off += (size_t)N * 4;
  int* bcnt  = (int*)(ws + off); off += NB_MAX * 4;
  int* bbase = (int*)(ws + off); off += NB_MAX * 4;
  int* bcur  = (int*)(ws + off); off += NB_MAX * 4;
  unsigned int* tmp = (unsigned int*)(ws + off); off += (size_t)E * 4;
  int* colp = (int*)(ws + off);

  int nb = (N + NB_ROWS - 1) >> NB_SHIFT;       // 489 for N=1e6

  hipMemsetAsync(bcnt, 0, NB_MAX * 4, stream);
  conv_wb<<<16, 256, 0, stream>>>(W, b, Wf, bf);
  proj<<<(N + 255) / 256, 256, 0, stream>>>(ego, Wf, bf, h, N);
  bhist<<<256, 256, 0, stream>>>(row, bcnt, E, nb);
  bscan<<<1, NB_MAX, 0, stream>>>(bcnt, bbase, bcur, nb);
  binpairs<<<(E + BP_EDGES - 1) / BP_EDGES, 256, 0, stream>>>(row, col, bcur, tmp, E, nb);
  csrbuild<<<nb, 512, 0, stream>>>(tmp, bbase, bcnt, deg, offs, colp, N);
  dim3 g((N + 255) / 256, 2);
  agg<<<g, 256, 0, stream>>>(h, offs, deg, colp, out, N);
}

// Round 3
// 1025.722 us; speedup vs baseline: 1.9086x; 1.2421x over previous
//
#include <hip/hip_runtime.h>
#include <hip/hip_fp16.h>
#include <stdint.h>

#define NEG_SLOPE 0.01f
#define EPSF 1e-10f
#define NB_SHIFT 11
#define NB_ROWS (1 << NB_SHIFT)   // 2048 rows per bucket
#define NB_MAX 512                // supports N up to 2^20
#define BP_EPT 16
#define BP_EDGES (256 * BP_EPT)   // 4096 edges per binpairs block
#define CB_CAP 20480              // csrbuild LDS staging capacity

__device__ __forceinline__ float lrelu(float x){
  return fmaxf(x, 0.f) + NEG_SLOPE * fminf(x, 0.f);
}

__device__ __forceinline__ unsigned pkh2(float a, float b){
  __half2 h = __floats2half2_rn(a, b);
  return __builtin_bit_cast(unsigned, h);
}

__device__ __forceinline__ float2 uph2(unsigned u){
  return __half22float2(__builtin_bit_cast(__half2, u));
}

// K0: repack W [2][64][32] fp32 -> Wf [64 k][64 j] (j = c*32+jj), b -> bf[64]
__global__ void conv_wb(const float* __restrict__ W,
                        const float* __restrict__ b,
                        float* __restrict__ Wf, float* __restrict__ bf){
  int i = blockIdx.x * blockDim.x + threadIdx.x;
  for (int idx = i; idx < 64 * 64; idx += blockDim.x * gridDim.x){
    int k = idx >> 6, j = idx & 63;
    int c = j >> 5, jj = j & 31;
    Wf[idx] = W[c * 2048 + k * 32 + jj];
  }
  if (i < 64) bf[i] = b[i];
}

// K1: projection -> fp16 h2 [n][64] (128B rows, LLC-resident working set)
__global__ __launch_bounds__(256) void proj(const float* __restrict__ ego,
                                            const float* __restrict__ Wf,
                                            const float* __restrict__ bf,
                                            __half* __restrict__ h2, int N){
  int n = blockIdx.x * 256 + threadIdx.x;
  if (n >= N) return;
  float acc[64];
  #pragma unroll
  for (int j = 0; j < 64; j++) acc[j] = bf[j];
  const float4* ep = (const float4*)(ego + (size_t)n * 64);
  for (int kk = 0; kk < 16; kk++){
    float4 q = ep[kk];
    float ev[4] = {q.x, q.y, q.z, q.w};
    const float* wbase = Wf + kk * 4 * 64;
    #pragma unroll
    for (int t = 0; t < 4; t++){
      float ek = ev[t];
      const float* wrow = wbase + t * 64;
      #pragma unroll
      for (int j = 0; j < 64; j++) acc[j] = fmaf(ek, wrow[j], acc[j]);
    }
  }
  uint4* dst = (uint4*)(h2 + (size_t)n * 64);
  #pragma unroll
  for (int v = 0; v < 8; v++){
    uint4 o;
    o.x = pkh2(lrelu(acc[8 * v + 0]), lrelu(acc[8 * v + 1]));
    o.y = pkh2(lrelu(acc[8 * v + 2]), lrelu(acc[8 * v + 3]));
    o.z = pkh2(lrelu(acc[8 * v + 4]), lrelu(acc[8 * v + 5]));
    o.w = pkh2(lrelu(acc[8 * v + 6]), lrelu(acc[8 * v + 7]));
    dst[v] = o;
  }
}

// K2: bucket histogram (LDS-staged). bucket = row >> NB_SHIFT
__global__ __launch_bounds__(256) void bhist(const int* __restrict__ row,
                                             int* __restrict__ bcnt, int E, int nb){
  __shared__ int lh[NB_MAX];
  for (int i = threadIdx.x; i < nb; i += 256) lh[i] = 0;
  __syncthreads();
  int i = blockIdx.x * 256 + threadIdx.x;
  int stride = gridDim.x * 256;
  for (; i < E; i += stride) atomicAdd(&lh[row[i] >> NB_SHIFT], 1);
  __syncthreads();
  for (int j = threadIdx.x; j < nb; j += 256){
    int v = lh[j];
    if (v) atomicAdd(&bcnt[j], v);
  }
}

// K3: exclusive scan of bucket counts, init bucket cursors
__global__ __launch_bounds__(512) void bscan(const int* __restrict__ bcnt,
                                             int* __restrict__ bbase,
                                             int* __restrict__ bcur, int nb){
  __shared__ int sh[NB_MAX];
  int t = threadIdx.x;
  int v = (t < nb) ? bcnt[t] : 0;
  sh[t] = v; __syncthreads();
  for (int off = 1; off < NB_MAX; off <<= 1){
    int a = (t >= off) ? sh[t - off] : 0;
    __syncthreads();
    sh[t] += a;
    __syncthreads();
  }
  if (t < nb){
    int e = sh[t] - v;
    bbase[t] = e;
    bcur[t] = e;
  }
}

// K4: bin edges into bucket-contiguous tmp, LDS-sorted so global writes
// are coalesced within per-(block,bucket) runs. packed = (rowLow11<<20)|col
__global__ __launch_bounds__(256) void binpairs(const int* __restrict__ row,
                                                const int* __restrict__ col,
                                                int* __restrict__ bcur,
                                                unsigned int* __restrict__ tmp,
                                                int E, int nb){
  __shared__ int lh[NB_MAX];
  __shared__ int lofs[NB_MAX];
  __shared__ int lbase[NB_MAX];
  __shared__ int wsum[256];
  __shared__ unsigned int sval[BP_EDGES];
  __shared__ unsigned int sdst[BP_EDGES];
  int t = threadIdx.x;
  for (int i = t; i < nb; i += 256) lh[i] = 0;
  __syncthreads();
  int e0 = blockIdx.x * BP_EDGES;
  int tot = E - e0; if (tot > BP_EDGES) tot = BP_EDGES;
  int r[BP_EPT], c[BP_EPT], mo[BP_EPT];
  #pragma unroll
  for (int k = 0; k < BP_EPT; k++){
    int e = e0 + k * 256 + t;
    if (e < E){
      r[k] = row[e];
      c[k] = col[e];
      mo[k] = atomicAdd(&lh[r[k] >> NB_SHIFT], 1);
    } else r[k] = -1;
  }
  __syncthreads();
  int c0 = (2 * t < nb) ? lh[2 * t] : 0;
  int c1 = (2 * t + 1 < nb) ? lh[2 * t + 1] : 0;
  int s = c0 + c1;
  wsum[t] = s; __syncthreads();
  for (int off = 1; off < 256; off <<= 1){
    int a = (t >= off) ? wsum[t - off] : 0;
    __syncthreads();
    wsum[t] += a;
    __syncthreads();
  }
  int tb = wsum[t] - s;
  if (2 * t < nb){
    lofs[2 * t] = tb;
    if (c0) lbase[2 * t] = atomicAdd(&bcur[2 * t], c0);
  }
  if (2 * t + 1 < nb){
    lofs[2 * t + 1] = tb + c0;
    if (c1) lbase[2 * t + 1] = atomicAdd(&bcur[2 * t + 1], c1);
  }
  __syncthreads();
  #pragma unroll
  for (int k = 0; k < BP_EPT; k++){
    if (r[k] >= 0){
      int b = r[k] >> NB_SHIFT;
      int slot = lofs[b] + mo[k];
      sval[slot] = ((unsigned int)(r[k] & (NB_ROWS - 1)) << 20) | (unsigned int)c[k];
      sdst[slot] = (unsigned int)(lbase[b] + mo[k]);
    }
  }
  __syncthreads();
  for (int i = t; i < tot; i += 256) tmp[sdst[i]] = sval[i];
}

// K5: per-bucket CSR finalize -> odeg (offs,deg packed) + colp
__global__ __launch_bounds__(512) void csrbuild(const unsigned int* __restrict__ tmp,
                                                const int* __restrict__ bbase,
                                                const int* __restrict__ bcnt,
                                                int2* __restrict__ odeg,
                                                int* __restrict__ colp,
                                                int N){
  __shared__ int cnt[NB_ROWS];
  __shared__ int wsum[512];
  __shared__ int scol[CB_CAP];
  int b = blockIdx.x;
  int r0 = b << NB_SHIFT;
  int t = threadIdx.x;
  for (int i = t; i < NB_ROWS; i += 512) cnt[i] = 0;
  __syncthreads();
  int s = bbase[b];
  int cb = bcnt[b];
  int e = s + cb;
  for (int p = s + t; p < e; p += 512) atomicAdd(&cnt[tmp[p] >> 20], 1);
  __syncthreads();
  int base_i = t * 4;
  int dv[4], loc[4];
  int sum = 0;
  #pragma unroll
  for (int k = 0; k < 4; k++){
    dv[k] = cnt[base_i + k];
    loc[k] = sum;
    sum += dv[k];
  }
  wsum[t] = sum; __syncthreads();
  for (int off = 1; off < 512; off <<= 1){
    int a = (t >= off) ? wsum[t - off] : 0;
    __syncthreads();
    wsum[t] += a;
    __syncthreads();
  }
  int tbase = wsum[t] - sum;
  #pragma unroll
  for (int k = 0; k < 4; k++){
    int i = base_i + k;
    int o = tbase + loc[k];
    if (r0 + i < N) odeg[r0 + i] = make_int2(s + o, dv[k]);
    cnt[i] = o;
  }
  __syncthreads();
  if (cb <= CB_CAP){
    for (int p = s + t; p < e; p += 512){
      unsigned int v = tmp[p];
      int pos = atomicAdd(&cnt[v >> 20], 1);
      scol[pos] = (int)(v & 0xFFFFFu);
    }
    __syncthreads();
    for (int i = t; i < cb; i += 512) colp[s + i] = scol[i];
  } else {
    for (int p = s + t; p < e; p += 512){
      unsigned int v = tmp[p];
      int pos = atomicAdd(&cnt[v >> 20], 1);
      colp[s + pos] = (int)(v & 0xFFFFFu);
    }
  }
}

// K6: fused dual-channel attention aggregation from fp16 h2.
// One 128B random row read per edge serves both channels; full 256B
// contiguous output rows (no write amplification).
__global__ __launch_bounds__(256) void agg2(const __half* __restrict__ h2,
                                            const int2* __restrict__ odeg,
                                            const int* __restrict__ colp,
                                            float* __restrict__ out, int N){
  int n = blockIdx.x * 256 + threadIdx.x;
  if (n >= N) return;
  unsigned hrp[32];
  const uint4* hr4 = (const uint4*)(h2 + (size_t)n * 64);
  #pragma unroll
  for (int v = 0; v < 8; v++){
    uint4 q = hr4[v];
    hrp[4 * v + 0] = q.x; hrp[4 * v + 1] = q.y;
    hrp[4 * v + 2] = q.z; hrp[4 * v + 3] = q.w;
  }
  float acc[64];
  #pragma unroll
  for (int j = 0; j < 64; j++) acc[j] = 0.f;
  float l0 = 0.f, l1 = 0.f;
  int2 od = odeg[n];
  int s = od.x, d = od.y;
  for (int p = s; p < s + d; ++p){
    int c = colp[p];
    unsigned hcp[32];
    const uint4* hc4 = (const uint4*)(h2 + (size_t)c * 64);
    #pragma unroll
    for (int v = 0; v < 8; v++){
      uint4 q = hc4[v];
      hcp[4 * v + 0] = q.x; hcp[4 * v + 1] = q.y;
      hcp[4 * v + 2] = q.z; hcp[4 * v + 3] = q.w;
    }
    float dot0 = 0.f, dot1 = 0.f;
    #pragma unroll
    for (int i = 0; i < 16; i++){
      float2 a = uph2(hrp[i]);
      float2 b = uph2(hcp[i]);
      dot0 = fmaf(a.x, b.x, dot0);
      dot0 = fmaf(a.y, b.y, dot0);
    }
    #pragma unroll
    for (int i = 16; i < 32; i++){
      float2 a = uph2(hrp[i]);
      float2 b = uph2(hcp[i]);
      dot1 = fmaf(a.x, b.x, dot1);
      dot1 = fmaf(a.y, b.y, dot1);
    }
    float w0 = __expf(fminf(lrelu(dot0), 80.f));
    float w1 = __expf(fminf(lrelu(dot1), 80.f));
    l0 += w0; l1 += w1;
    #pragma unroll
    for (int i = 0; i < 16; i++){
      float2 b = uph2(hcp[i]);
      acc[2 * i + 0] = fmaf(w0, b.x, acc[2 * i + 0]);
      acc[2 * i + 1] = fmaf(w0, b.y, acc[2 * i + 1]);
    }
    #pragma unroll
    for (int i = 16; i < 32; i++){
      float2 b = uph2(hcp[i]);
      acc[2 * i + 0] = fmaf(w1, b.x, acc[2 * i + 0]);
      acc[2 * i + 1] = fmaf(w1, b.y, acc[2 * i + 1]);
    }
  }
  float inv0 = 1.f / (l0 + EPSF);
  float inv1 = 1.f / (l1 + EPSF);
  float4* op = (float4*)(out + (size_t)n * 64);
  #pragma unroll
  for (int v = 0; v < 16; v++){
    float sc = (v < 8) ? inv0 : inv1;
    float4 o;
    o.x = acc[4 * v + 0] * sc;
    o.y = acc[4 * v + 1] * sc;
    o.z = acc[4 * v + 2] * sc;
    o.w = acc[4 * v + 3] * sc;
    op[v] = o;
  }
}

extern "C" void kernel_launch(void* const* d_in, const int* in_sizes, int n_in,
                              void* d_out, int out_size, void* d_ws, size_t ws_size,
                              hipStream_t stream){
  const float* ego = (const float*)d_in[0];
  const float* W   = (const float*)d_in[1];
  const float* b   = (const float*)d_in[2];
  const int* row = (const int*)d_in[3];
  const int* col = (const int*)d_in[4];
  int N = in_sizes[0] / 64;
  int E = in_sizes[3];
  float* out = (float*)d_out;

  char* ws = (char*)d_ws;
  float* Wf = (float*)ws;                       // 4096 f
  float* bf = Wf + 4096;                        // 64 f
  size_t off = 32768;
  __half* h2 = (__half*)(ws + off); off += (size_t)N * 64 * 2;
  int2* odeg = (int2*)(ws + off); off += (size_t)N * 8;
  int* bcnt  = (int*)(ws + off); off += NB_MAX * 4;
  int* bbase = (int*)(ws + off); off += NB_MAX * 4;
  int* bcur  = (int*)(ws + off); off += NB_MAX * 4;
  unsigned int* tmp = (unsigned int*)(ws + off); off += (size_t)E * 4;
  int* colp = (int*)(ws + off);

  int nb = (N + NB_ROWS - 1) >> NB_SHIFT;       // 489 for N=1e6

  hipMemsetAsync(bcnt, 0, NB_MAX * 4, stream);
  conv_wb<<<16, 256, 0, stream>>>(W, b, Wf, bf);
  proj<<<(N + 255) / 256, 256, 0, stream>>>(ego, Wf, bf, h2, N);
  bhist<<<1024, 256, 0, stream>>>(row, bcnt, E, nb);
  bscan<<<1, NB_MAX, 0, stream>>>(bcnt, bbase, bcur, nb);
  binpairs<<<(E + BP_EDGES - 1) / BP_EDGES, 256, 0, stream>>>(row, col, bcur, tmp, E, nb);
  csrbuild<<<nb, 512, 0, stream>>>(tmp, bbase, bcnt, odeg, colp, N);
  agg2<<<(N + 255) / 256, 256, 0, stream>>>(h2, odeg, colp, out, N);
}